// Round 1
// baseline (3458.749 us; speedup 1.0000x reference)
//
#include <hip/hip_runtime.h>

typedef unsigned int u32;

#define N_TOK 65536
#define DIM 256
#define NE 4096
#define TM 128
#define TN 128
#define TK 32
#define LDX 36   // x-tile leading dim (floats): 32 + 4 pad, 16B-aligned rows
#define LDE 132  // e-tile leading dim (floats): 128 + 4 pad

__device__ __align__(16) float g_enorm[NE];     // np-exact sum(embed^2, axis=0)
__device__ __align__(16) float g_xnorm[N_TOK];  // np-exact sum(x^2, axis=1)
__device__ float g_diffarr[64];                 // diff partial bins

__device__ __forceinline__ float sqr_rn(float v) { return __fmul_rn(v, v); }

// NumPy pairwise_sum for a 128-block of squares: 8 accumulators, 8-way unrolled,
// combine ((r0+r1)+(r2+r3)) + ((r4+r5)+(r6+r7)). Non-fused (matches temp-array sum).
__device__ float np_sum128_sq(const float* __restrict__ a) {
    float r[8];
#pragma unroll
    for (int j = 0; j < 8; ++j) r[j] = sqr_rn(a[j]);
    for (int i = 8; i < 128; i += 8)
#pragma unroll
        for (int j = 0; j < 8; ++j) r[j] = __fadd_rn(r[j], sqr_rn(a[i + j]));
    return __fadd_rn(__fadd_rn(__fadd_rn(r[0], r[1]), __fadd_rn(r[2], r[3])),
                     __fadd_rn(__fadd_rn(r[4], r[5]), __fadd_rn(r[6], r[7])));
}

// ---------------- K1a: x row norms, np-pairwise bit-exact (n=256 -> 128+128) --
__global__ void k_xnorm(const float* __restrict__ x) {
    const int n = blockIdx.x * 256 + threadIdx.x;
    const float* row = x + (size_t)n * DIM;
    g_xnorm[n] = __fadd_rn(np_sum128_sq(row), np_sum128_sq(row + 128));
    if (blockIdx.x == 0 && threadIdx.x < 64) g_diffarr[threadIdx.x] = 0.f;
}

// ---------------- K1b: embed col norms, np axis-0 sequential bit-exact -------
__global__ void k_enorm(const float* __restrict__ embed) {
    const int e = blockIdx.x * 256 + threadIdx.x;  // coalesced over e
    float s = sqr_rn(embed[e]);
    for (int d = 1; d < DIM; ++d) s = __fadd_rn(s, sqr_rn(embed[(size_t)d * NE + e]));
    g_enorm[e] = s;
}

// ---------------- K2: distance GEMM + argmin, bit-matching np float32 --------
// dot: single sequential fp32 FMA chain over k=0..255 ascending (== BLAS microkernel).
// score = (xnorm - 2*dot) + enorm, each op fp32-rounded (np left-to-right).
// argmax(-dist) == first occurrence of min -> strict < with ascending-e scan.
// 8x8 per-thread tile: 256 FMAs per 16 ds_read_b128 (1.5x the old 8x4 ratio);
// LDS 34.5 KB -> 3 blocks/CU (12 waves/CU) via launch_bounds(256,3).
__global__ __launch_bounds__(256, 3)
void k_argmin(const float* __restrict__ x, const float* __restrict__ embed,
              float* __restrict__ out_ind) {
    __shared__ float xs[TM * LDX];  // 128 x 32 (+pad) = 18.4 KB
    __shared__ float es[TK * LDE];  // 32 x 128 (+pad) = 16.9 KB
    const int tid = threadIdx.x;
    const int tx = tid & 15;        // 16 code-lanes x 8 consecutive codes = 128
    const int ty = tid >> 4;        // token rows r = i*16 + ty
    const int n0 = blockIdx.x * TM;

    float xn[8];
#pragma unroll
    for (int i = 0; i < 8; i++) xn[i] = g_xnorm[n0 + i * 16 + ty];

    float best[8];
    int bidx[8];
#pragma unroll
    for (int i = 0; i < 8; i++) { best[i] = 3.0e38f; bidx[i] = 0; }

    for (int et = 0; et < NE / TN; ++et) {
        const int e0 = et * TN;
        float acc[8][8];
#pragma unroll
        for (int i = 0; i < 8; i++)
#pragma unroll
            for (int j = 0; j < 8; j++) acc[i][j] = 0.f;

        for (int kt = 0; kt < DIM / TK; ++kt) {
            const int k0 = kt * TK;
            __syncthreads();
#pragma unroll
            for (int i = 0; i < 4; i++) {  // x tile 128x32: 1024 float4
                int f = tid + i * 256;
                int r = f >> 3, c4 = f & 7;
                *(float4*)&xs[r * LDX + c4 * 4] =
                    *(const float4*)(x + (size_t)(n0 + r) * DIM + k0 + c4 * 4);
            }
#pragma unroll
            for (int i = 0; i < 4; i++) {  // embed tile 32x128: 1024 float4
                int f = tid + i * 256;
                int r = f >> 5, c4 = f & 31;
                *(float4*)&es[r * LDE + c4 * 4] =
                    *(const float4*)(embed + (size_t)(k0 + r) * NE + e0 + c4 * 4);
            }
            __syncthreads();
#pragma unroll 2
            for (int g = 0; g < TK / 4; ++g) {
                const int k = g * 4;
                float ev[4][8];
#pragma unroll
                for (int kk = 0; kk < 4; kk++) {  // 16-lane x 4-way-broadcast reads
                    float4 a = *(const float4*)&es[(k + kk) * LDE + tx * 8];
                    float4 b = *(const float4*)&es[(k + kk) * LDE + tx * 8 + 4];
                    ev[kk][0] = a.x; ev[kk][1] = a.y; ev[kk][2] = a.z; ev[kk][3] = a.w;
                    ev[kk][4] = b.x; ev[kk][5] = b.y; ev[kk][6] = b.z; ev[kk][7] = b.w;
                }
#pragma unroll
                for (int i = 0; i < 8; i++) {
                    float4 xt = *(const float4*)&xs[(i * 16 + ty) * LDX + k];
                    float xk[4] = {xt.x, xt.y, xt.z, xt.w};
#pragma unroll
                    for (int kk = 0; kk < 4; kk++)   // k ascending: one FMA chain
#pragma unroll
                        for (int j = 0; j < 8; j++)
                            acc[i][j] = fmaf(xk[kk], ev[kk][j], acc[i][j]);
                }
            }
        }
        const float4 en4a = *(const float4*)&g_enorm[e0 + tx * 8];
        const float4 en4b = *(const float4*)&g_enorm[e0 + tx * 8 + 4];
        const float enj[8] = {en4a.x, en4a.y, en4a.z, en4a.w,
                              en4b.x, en4b.y, en4b.z, en4b.w};
#pragma unroll
        for (int i = 0; i < 8; i++) {
#pragma unroll
            for (int j = 0; j < 8; j++) {
                // np: ((xnorm - 2*mm) + enorm), each fp32-rounded
                float v = __fadd_rn(__fsub_rn(xn[i], __fmul_rn(2.0f, acc[i][j])), enj[j]);
                int e = e0 + tx * 8 + j;
                if (v < best[i]) { best[i] = v; bidx[i] = e; }
            }
        }
    }
    // reduce across the 16 tx lanes per token row; ties -> smaller index (np first-min)
#pragma unroll
    for (int i = 0; i < 8; i++) {
        float b = best[i];
        int bi = bidx[i];
#pragma unroll
        for (int m = 1; m < 16; m <<= 1) {
            float ob = __shfl_xor(b, m, 64);
            int oi = __shfl_xor(bi, m, 64);
            if (ob < b || (ob == b && oi < bi)) { b = ob; bi = oi; }
        }
        if (tx == 0) out_ind[n0 + i * 16 + ty] = (float)bi;
    }
}

// ---------------- K3: gather quantize (fp32) + diff partials -----------------
__global__ void k_gather(const float* __restrict__ x, const float* __restrict__ embed,
                         const float* __restrict__ out_ind, float* __restrict__ outq) {
    const int n = blockIdx.x;
    const int d = threadIdx.x;
    int e = (int)out_ind[n];
    e = e < 0 ? 0 : (e > NE - 1 ? NE - 1 : e);  // OOB-proof
    const float v = embed[(size_t)d * NE + e];
    outq[(size_t)n * DIM + d] = v;
    float sq = v - x[(size_t)n * DIM + d];
    sq *= sq;
#pragma unroll
    for (int m = 1; m < 64; m <<= 1) sq += __shfl_xor(sq, m, 64);
    __shared__ float wsum[4];
    if ((d & 63) == 0) wsum[d >> 6] = sq;
    __syncthreads();
    if (d == 0) atomicAdd(&g_diffarr[n & 63], wsum[0] + wsum[1] + wsum[2] + wsum[3]);
}

// ---------------- K4: publish diff -------------------------------------------
__global__ void k_finish(float* __restrict__ out_diff) {
    float t = 0.f;
    for (int w = 0; w < 64; ++w) t += g_diffarr[w];
    if (threadIdx.x == 0) *out_diff = t * (1.0f / 16777216.0f);
}

extern "C" void kernel_launch(void* const* d_in, const int* in_sizes, int n_in,
                              void* d_out, int out_size, void* d_ws, size_t ws_size,
                              hipStream_t stream) {
    // fp32 in / fp32 out. Output 2 must bit-match the np float32 reference:
    // sequential-FMA sgemm chain + np pairwise/sequential norms.
    const float* x = (const float*)d_in[0];      // [65536, 256]
    const float* embed = (const float*)d_in[1];  // [256, 4096]
    float* outq = (float*)d_out;                 // quantize: [0, 16777216)
    float* out_diff = outq + 16777216;           // diff scalar
    float* out_ind = outq + 16777217;            // embed_ind (float-coded): 65536

    hipLaunchKernelGGL(k_xnorm, dim3(N_TOK / 256), dim3(256), 0, stream, x);
    hipLaunchKernelGGL(k_enorm, dim3(NE / 256), dim3(256), 0, stream, embed);
    hipLaunchKernelGGL(k_argmin, dim3(N_TOK / TM), dim3(256), 0, stream, x, embed, out_ind);
    hipLaunchKernelGGL(k_gather, dim3(N_TOK), dim3(256), 0, stream, x, embed, out_ind, outq);
    hipLaunchKernelGGL(k_finish, dim3(1), dim3(64), 0, stream, out_diff);
}

// Round 2
// 2519.175 us; speedup vs baseline: 1.3730x; 1.3730x over previous
//
#include <hip/hip_runtime.h>

typedef unsigned int u32;

#define N_TOK 65536
#define DIM 256
#define NE 4096
#define TM 128
#define TN 128
#define TK 32
#define LDX 36   // x-tile leading dim (floats): 32 + 4 pad, 16B-aligned rows
#define LDE 132  // e-tile leading dim (floats): 128 + 4 pad

__device__ __align__(16) float g_enorm[NE];     // np-exact sum(embed^2, axis=0)
__device__ __align__(16) float g_xnorm[N_TOK];  // np-exact sum(x^2, axis=1)
__device__ float g_diffarr[64];                 // diff partial bins

__device__ __forceinline__ float sqr_rn(float v) { return __fmul_rn(v, v); }

// NumPy pairwise_sum for a 128-block of squares: 8 accumulators, 8-way unrolled,
// combine ((r0+r1)+(r2+r3)) + ((r4+r5)+(r6+r7)). Non-fused (matches temp-array sum).
__device__ float np_sum128_sq(const float* __restrict__ a) {
    float r[8];
#pragma unroll
    for (int j = 0; j < 8; ++j) r[j] = sqr_rn(a[j]);
    for (int i = 8; i < 128; i += 8)
#pragma unroll
        for (int j = 0; j < 8; ++j) r[j] = __fadd_rn(r[j], sqr_rn(a[i + j]));
    return __fadd_rn(__fadd_rn(__fadd_rn(r[0], r[1]), __fadd_rn(r[2], r[3])),
                     __fadd_rn(__fadd_rn(r[4], r[5]), __fadd_rn(r[6], r[7])));
}

// ---------------- K1a: x row norms, np-pairwise bit-exact (n=256 -> 128+128) --
__global__ void k_xnorm(const float* __restrict__ x) {
    const int n = blockIdx.x * 256 + threadIdx.x;
    const float* row = x + (size_t)n * DIM;
    g_xnorm[n] = __fadd_rn(np_sum128_sq(row), np_sum128_sq(row + 128));
    if (blockIdx.x == 0 && threadIdx.x < 64) g_diffarr[threadIdx.x] = 0.f;
}

// ---------------- K1b: embed col norms, np axis-0 sequential bit-exact -------
__global__ void k_enorm(const float* __restrict__ embed) {
    const int e = blockIdx.x * 256 + threadIdx.x;  // coalesced over e
    float s = sqr_rn(embed[e]);
    for (int d = 1; d < DIM; ++d) s = __fadd_rn(s, sqr_rn(embed[(size_t)d * NE + e]));
    g_enorm[e] = s;
}

// ---------------- K2: distance GEMM + argmin, bit-matching np float32 --------
// dot: single sequential fp32 FMA chain over k=0..255 ascending (== BLAS microkernel).
// score = (xnorm - 2*dot) + enorm, each op fp32-rounded (np left-to-right).
// argmax(-dist) == first occurrence of min -> strict < with ascending-e scan.
// 8x8 per-thread tile: 256 FMAs per 16 ds_read_b128.
// Thread's 8 codes = {e0+tx*4+j} and {e0+64+tx*4+j}: ev reads at tx*4 spacing
// are 2-way bank aliases (free, m136) vs 4-way at tx*8 (R1's 1.34e8 conflicts).
// launch_bounds(256,2): 256-VGPR cap -> no scratch spill (R1's 2.2GB WRITE_SIZE
// came from the 168-cap + unroll-2 keeping 2x ev[4][8] live -> acc spilled).
__global__ __launch_bounds__(256, 2)
void k_argmin(const float* __restrict__ x, const float* __restrict__ embed,
              float* __restrict__ out_ind) {
    __shared__ float xs[TM * LDX];  // 128 x 32 (+pad) = 18.4 KB
    __shared__ float es[TK * LDE];  // 32 x 128 (+pad) = 16.9 KB
    const int tid = threadIdx.x;
    const int tx = tid & 15;        // 16 code-lanes; codes tx*4..+3 and 64+tx*4..+3
    const int ty = tid >> 4;        // token rows r = i*16 + ty
    const int n0 = blockIdx.x * TM;

    float xn[8];
#pragma unroll
    for (int i = 0; i < 8; i++) xn[i] = g_xnorm[n0 + i * 16 + ty];

    float best[8];
    int bidx[8];
#pragma unroll
    for (int i = 0; i < 8; i++) { best[i] = 3.0e38f; bidx[i] = 0; }

    for (int et = 0; et < NE / TN; ++et) {
        const int e0 = et * TN;
        float acc[8][8];
#pragma unroll
        for (int i = 0; i < 8; i++)
#pragma unroll
            for (int j = 0; j < 8; j++) acc[i][j] = 0.f;

        for (int kt = 0; kt < DIM / TK; ++kt) {
            const int k0 = kt * TK;
            __syncthreads();
#pragma unroll
            for (int i = 0; i < 4; i++) {  // x tile 128x32: 1024 float4
                int f = tid + i * 256;
                int r = f >> 3, c4 = f & 7;
                *(float4*)&xs[r * LDX + c4 * 4] =
                    *(const float4*)(x + (size_t)(n0 + r) * DIM + k0 + c4 * 4);
            }
#pragma unroll
            for (int i = 0; i < 4; i++) {  // embed tile 32x128: 1024 float4
                int f = tid + i * 256;
                int r = f >> 5, c4 = f & 31;
                *(float4*)&es[r * LDE + c4 * 4] =
                    *(const float4*)(embed + (size_t)(k0 + r) * NE + e0 + c4 * 4);
            }
            __syncthreads();
#pragma unroll 1
            for (int g = 0; g < TK / 4; ++g) {
                const int k = g * 4;
                float ev[4][8];
#pragma unroll
                for (int kk = 0; kk < 4; kk++) {  // 2x float4, 64 floats apart: 2-way free
                    float4 a = *(const float4*)&es[(k + kk) * LDE + tx * 4];
                    float4 b = *(const float4*)&es[(k + kk) * LDE + 64 + tx * 4];
                    ev[kk][0] = a.x; ev[kk][1] = a.y; ev[kk][2] = a.z; ev[kk][3] = a.w;
                    ev[kk][4] = b.x; ev[kk][5] = b.y; ev[kk][6] = b.z; ev[kk][7] = b.w;
                }
#pragma unroll
                for (int i = 0; i < 8; i++) {
                    float4 xt = *(const float4*)&xs[(i * 16 + ty) * LDX + k];
                    float xk[4] = {xt.x, xt.y, xt.z, xt.w};
#pragma unroll
                    for (int kk = 0; kk < 4; kk++)   // k ascending: one FMA chain
#pragma unroll
                        for (int j = 0; j < 8; j++)
                            acc[i][j] = fmaf(xk[kk], ev[kk][j], acc[i][j]);
                }
            }
        }
        const float4 en4a = *(const float4*)&g_enorm[e0 + tx * 4];
        const float4 en4b = *(const float4*)&g_enorm[e0 + 64 + tx * 4];
        const float enj[8] = {en4a.x, en4a.y, en4a.z, en4a.w,
                              en4b.x, en4b.y, en4b.z, en4b.w};
#pragma unroll
        for (int i = 0; i < 8; i++) {
            // within-thread scan order ascending in e: tx*4+j (j<4) then 64+tx*4+j
#pragma unroll
            for (int j = 0; j < 8; j++) {
                // np: ((xnorm - 2*mm) + enorm), each fp32-rounded
                float v = __fadd_rn(__fsub_rn(xn[i], __fmul_rn(2.0f, acc[i][j])), enj[j]);
                int e = e0 + (j < 4 ? tx * 4 + j : 64 + tx * 4 + (j - 4));
                if (v < best[i]) { best[i] = v; bidx[i] = e; }
            }
        }
    }
    // reduce across the 16 tx lanes per token row; ties -> smaller index (np first-min)
#pragma unroll
    for (int i = 0; i < 8; i++) {
        float b = best[i];
        int bi = bidx[i];
#pragma unroll
        for (int m = 1; m < 16; m <<= 1) {
            float ob = __shfl_xor(b, m, 64);
            int oi = __shfl_xor(bi, m, 64);
            if (ob < b || (ob == b && oi < bi)) { b = ob; bi = oi; }
        }
        if (tx == 0) out_ind[n0 + i * 16 + ty] = (float)bi;
    }
}

// ---------------- K3: gather quantize (fp32) + diff partials -----------------
__global__ void k_gather(const float* __restrict__ x, const float* __restrict__ embed,
                         const float* __restrict__ out_ind, float* __restrict__ outq) {
    const int n = blockIdx.x;
    const int d = threadIdx.x;
    int e = (int)out_ind[n];
    e = e < 0 ? 0 : (e > NE - 1 ? NE - 1 : e);  // OOB-proof
    const float v = embed[(size_t)d * NE + e];
    outq[(size_t)n * DIM + d] = v;
    float sq = v - x[(size_t)n * DIM + d];
    sq *= sq;
#pragma unroll
    for (int m = 1; m < 64; m <<= 1) sq += __shfl_xor(sq, m, 64);
    __shared__ float wsum[4];
    if ((d & 63) == 0) wsum[d >> 6] = sq;
    __syncthreads();
    if (d == 0) atomicAdd(&g_diffarr[n & 63], wsum[0] + wsum[1] + wsum[2] + wsum[3]);
}

// ---------------- K4: publish diff -------------------------------------------
__global__ void k_finish(float* __restrict__ out_diff) {
    float t = 0.f;
    for (int w = 0; w < 64; ++w) t += g_diffarr[w];
    if (threadIdx.x == 0) *out_diff = t * (1.0f / 16777216.0f);
}

extern "C" void kernel_launch(void* const* d_in, const int* in_sizes, int n_in,
                              void* d_out, int out_size, void* d_ws, size_t ws_size,
                              hipStream_t stream) {
    // fp32 in / fp32 out. Output 2 must bit-match the np float32 reference:
    // sequential-FMA sgemm chain + np pairwise/sequential norms.
    const float* x = (const float*)d_in[0];      // [65536, 256]
    const float* embed = (const float*)d_in[1];  // [256, 4096]
    float* outq = (float*)d_out;                 // quantize: [0, 16777216)
    float* out_diff = outq + 16777216;           // diff scalar
    float* out_ind = outq + 16777217;            // embed_ind (float-coded): 65536

    hipLaunchKernelGGL(k_xnorm, dim3(N_TOK / 256), dim3(256), 0, stream, x);
    hipLaunchKernelGGL(k_enorm, dim3(NE / 256), dim3(256), 0, stream, embed);
    hipLaunchKernelGGL(k_argmin, dim3(N_TOK / TM), dim3(256), 0, stream, x, embed, out_ind);
    hipLaunchKernelGGL(k_gather, dim3(N_TOK), dim3(256), 0, stream, x, embed, out_ind, outq);
    hipLaunchKernelGGL(k_finish, dim3(1), dim3(64), 0, stream, out_diff);
}

// Round 3
// 2498.744 us; speedup vs baseline: 1.3842x; 1.0082x over previous
//
#include <hip/hip_runtime.h>

typedef unsigned int u32;

#define N_TOK 65536
#define DIM 256
#define NE 4096
#define TM 128
#define TN 128
#define TK 32
#define LDX 36   // x-tile leading dim (floats): 32 + 4 pad, 16B-aligned rows
#define LDE 132  // e-tile leading dim (floats): 128 + 4 pad
#define EHALF 2  // grid split over code range: 2x blocks -> 4 blocks/CU

__device__ __align__(16) float g_enorm[NE];     // np-exact sum(embed^2, axis=0)
__device__ __align__(16) float g_xnorm[N_TOK];  // np-exact sum(x^2, axis=1)
__device__ float g_diffarr[64];                 // diff partial bins
__device__ float g_best[EHALF][N_TOK];          // per-half min dist
__device__ float g_bidx[EHALF][N_TOK];          // per-half argmin (float-coded)

__device__ __forceinline__ float sqr_rn(float v) { return __fmul_rn(v, v); }

// NumPy pairwise_sum for a 128-block of squares: 8 accumulators, 8-way unrolled,
// combine ((r0+r1)+(r2+r3)) + ((r4+r5)+(r6+r7)). Non-fused (matches temp-array sum).
__device__ float np_sum128_sq(const float* __restrict__ a) {
    float r[8];
#pragma unroll
    for (int j = 0; j < 8; ++j) r[j] = sqr_rn(a[j]);
    for (int i = 8; i < 128; i += 8)
#pragma unroll
        for (int j = 0; j < 8; ++j) r[j] = __fadd_rn(r[j], sqr_rn(a[i + j]));
    return __fadd_rn(__fadd_rn(__fadd_rn(r[0], r[1]), __fadd_rn(r[2], r[3])),
                     __fadd_rn(__fadd_rn(r[4], r[5]), __fadd_rn(r[6], r[7])));
}

// ---------------- K1a: x row norms, np-pairwise bit-exact (n=256 -> 128+128) --
__global__ void k_xnorm(const float* __restrict__ x) {
    const int n = blockIdx.x * 256 + threadIdx.x;
    const float* row = x + (size_t)n * DIM;
    g_xnorm[n] = __fadd_rn(np_sum128_sq(row), np_sum128_sq(row + 128));
    if (blockIdx.x == 0 && threadIdx.x < 64) g_diffarr[threadIdx.x] = 0.f;
}

// ---------------- K1b: embed col norms, np axis-0 sequential bit-exact -------
__global__ void k_enorm(const float* __restrict__ embed) {
    const int e = blockIdx.x * 256 + threadIdx.x;  // coalesced over e
    float s = sqr_rn(embed[e]);
    for (int d = 1; d < DIM; ++d) s = __fadd_rn(s, sqr_rn(embed[(size_t)d * NE + e]));
    g_enorm[e] = s;
}

// ---------------- K2: distance GEMM + argmin, bit-matching np float32 --------
// dot: single sequential fp32 FMA chain over k=0..255 ascending (== BLAS microkernel).
// score = (xnorm - 2*dot) + enorm, each op fp32-rounded (np left-to-right).
// argmax(-dist) == first occurrence of min -> strict < with ascending-e scan.
// 8x8 per-thread tile: 256 FMAs per 16 ds_read_b128; ev reads at tx*4 spacing
// (2-way bank alias, free per m136).
// R3: grid split over the code range (blockIdx.y = half). 512 blocks was exactly
// 2 blocks/CU (grid-limited occupancy, 21%); 1024 blocks -> 4 blocks/CU,
// 16 waves/CU. Per-half scan is byte-identical to the full scan's subrange;
// merge (strict <, tie -> half0 = lower index) reproduces global first-min.
__global__ __launch_bounds__(256, 2)
void k_argmin(const float* __restrict__ x, const float* __restrict__ embed) {
    __shared__ float xs[TM * LDX];  // 128 x 32 (+pad) = 18.4 KB
    __shared__ float es[TK * LDE];  // 32 x 128 (+pad) = 16.9 KB
    const int tid = threadIdx.x;
    const int tx = tid & 15;        // 16 code-lanes; codes tx*4..+3 and 64+tx*4..+3
    const int ty = tid >> 4;        // token rows r = i*16 + ty
    const int n0 = blockIdx.x * TM;
    const int h = blockIdx.y;       // code half: et in [h*16, h*16+16)

    float xn[8];
#pragma unroll
    for (int i = 0; i < 8; i++) xn[i] = g_xnorm[n0 + i * 16 + ty];

    float best[8];
    int bidx[8];
#pragma unroll
    for (int i = 0; i < 8; i++) { best[i] = 3.0e38f; bidx[i] = 0; }

    const int et_lo = h * (NE / TN / EHALF);
    const int et_hi = et_lo + (NE / TN / EHALF);
    for (int et = et_lo; et < et_hi; ++et) {
        const int e0 = et * TN;
        float acc[8][8];
#pragma unroll
        for (int i = 0; i < 8; i++)
#pragma unroll
            for (int j = 0; j < 8; j++) acc[i][j] = 0.f;

        for (int kt = 0; kt < DIM / TK; ++kt) {
            const int k0 = kt * TK;
            __syncthreads();
#pragma unroll
            for (int i = 0; i < 4; i++) {  // x tile 128x32: 1024 float4
                int f = tid + i * 256;
                int r = f >> 3, c4 = f & 7;
                *(float4*)&xs[r * LDX + c4 * 4] =
                    *(const float4*)(x + (size_t)(n0 + r) * DIM + k0 + c4 * 4);
            }
#pragma unroll
            for (int i = 0; i < 4; i++) {  // embed tile 32x128: 1024 float4
                int f = tid + i * 256;
                int r = f >> 5, c4 = f & 31;
                *(float4*)&es[r * LDE + c4 * 4] =
                    *(const float4*)(embed + (size_t)(k0 + r) * NE + e0 + c4 * 4);
            }
            __syncthreads();
#pragma unroll 1
            for (int g = 0; g < TK / 4; ++g) {
                const int k = g * 4;
                float ev[4][8];
#pragma unroll
                for (int kk = 0; kk < 4; kk++) {  // 2x float4, 64 floats apart: 2-way free
                    float4 a = *(const float4*)&es[(k + kk) * LDE + tx * 4];
                    float4 b = *(const float4*)&es[(k + kk) * LDE + 64 + tx * 4];
                    ev[kk][0] = a.x; ev[kk][1] = a.y; ev[kk][2] = a.z; ev[kk][3] = a.w;
                    ev[kk][4] = b.x; ev[kk][5] = b.y; ev[kk][6] = b.z; ev[kk][7] = b.w;
                }
#pragma unroll
                for (int i = 0; i < 8; i++) {
                    float4 xt = *(const float4*)&xs[(i * 16 + ty) * LDX + k];
                    float xk[4] = {xt.x, xt.y, xt.z, xt.w};
#pragma unroll
                    for (int kk = 0; kk < 4; kk++)   // k ascending: one FMA chain
#pragma unroll
                        for (int j = 0; j < 8; j++)
                            acc[i][j] = fmaf(xk[kk], ev[kk][j], acc[i][j]);
                }
            }
        }
        const float4 en4a = *(const float4*)&g_enorm[e0 + tx * 4];
        const float4 en4b = *(const float4*)&g_enorm[e0 + 64 + tx * 4];
        const float enj[8] = {en4a.x, en4a.y, en4a.z, en4a.w,
                              en4b.x, en4b.y, en4b.z, en4b.w};
#pragma unroll
        for (int i = 0; i < 8; i++) {
            // within-thread scan order ascending in e: tx*4+j (j<4) then 64+tx*4+j
#pragma unroll
            for (int j = 0; j < 8; j++) {
                // np: ((xnorm - 2*mm) + enorm), each fp32-rounded
                float v = __fadd_rn(__fsub_rn(xn[i], __fmul_rn(2.0f, acc[i][j])), enj[j]);
                int e = e0 + (j < 4 ? tx * 4 + j : 64 + tx * 4 + (j - 4));
                if (v < best[i]) { best[i] = v; bidx[i] = e; }
            }
        }
    }
    // reduce across the 16 tx lanes per token row; ties -> smaller index (np first-min)
#pragma unroll
    for (int i = 0; i < 8; i++) {
        float b = best[i];
        int bi = bidx[i];
#pragma unroll
        for (int m = 1; m < 16; m <<= 1) {
            float ob = __shfl_xor(b, m, 64);
            int oi = __shfl_xor(bi, m, 64);
            if (ob < b || (ob == b && oi < bi)) { b = ob; bi = oi; }
        }
        if (tx == 0) {
            g_best[h][n0 + i * 16 + ty] = b;
            g_bidx[h][n0 + i * 16 + ty] = (float)bi;
        }
    }
}

// ---------------- K2b: merge per-half argmins ------------------------------
// Global first-min = strict < between halves; tie -> half0 (lower index). Exact.
__global__ void k_merge(float* __restrict__ out_ind) {
    const int n = blockIdx.x * 256 + threadIdx.x;
    const float b0 = g_best[0][n], b1 = g_best[1][n];
    const float i0 = g_bidx[0][n], i1 = g_bidx[1][n];
    out_ind[n] = (b1 < b0) ? i1 : i0;
}

// ---------------- K3: gather quantize (fp32) + diff partials -----------------
__global__ void k_gather(const float* __restrict__ x, const float* __restrict__ embed,
                         const float* __restrict__ out_ind, float* __restrict__ outq) {
    const int n = blockIdx.x;
    const int d = threadIdx.x;
    int e = (int)out_ind[n];
    e = e < 0 ? 0 : (e > NE - 1 ? NE - 1 : e);  // OOB-proof
    const float v = embed[(size_t)d * NE + e];
    outq[(size_t)n * DIM + d] = v;
    float sq = v - x[(size_t)n * DIM + d];
    sq *= sq;
#pragma unroll
    for (int m = 1; m < 64; m <<= 1) sq += __shfl_xor(sq, m, 64);
    __shared__ float wsum[4];
    if ((d & 63) == 0) wsum[d >> 6] = sq;
    __syncthreads();
    if (d == 0) atomicAdd(&g_diffarr[n & 63], wsum[0] + wsum[1] + wsum[2] + wsum[3]);
}

// ---------------- K4: publish diff -------------------------------------------
__global__ void k_finish(float* __restrict__ out_diff) {
    float t = 0.f;
    for (int w = 0; w < 64; ++w) t += g_diffarr[w];
    if (threadIdx.x == 0) *out_diff = t * (1.0f / 16777216.0f);
}

extern "C" void kernel_launch(void* const* d_in, const int* in_sizes, int n_in,
                              void* d_out, int out_size, void* d_ws, size_t ws_size,
                              hipStream_t stream) {
    // fp32 in / fp32 out. Output 2 must bit-match the np float32 reference:
    // sequential-FMA sgemm chain + np pairwise/sequential norms.
    const float* x = (const float*)d_in[0];      // [65536, 256]
    const float* embed = (const float*)d_in[1];  // [256, 4096]
    float* outq = (float*)d_out;                 // quantize: [0, 16777216)
    float* out_diff = outq + 16777216;           // diff scalar
    float* out_ind = outq + 16777217;            // embed_ind (float-coded): 65536

    hipLaunchKernelGGL(k_xnorm, dim3(N_TOK / 256), dim3(256), 0, stream, x);
    hipLaunchKernelGGL(k_enorm, dim3(NE / 256), dim3(256), 0, stream, embed);
    hipLaunchKernelGGL(k_argmin, dim3(N_TOK / TM, EHALF), dim3(256), 0, stream, x, embed);
    hipLaunchKernelGGL(k_merge, dim3(N_TOK / 256), dim3(256), 0, stream, out_ind);
    hipLaunchKernelGGL(k_gather, dim3(N_TOK), dim3(256), 0, stream, x, embed, out_ind, outq);
    hipLaunchKernelGGL(k_finish, dim3(1), dim3(64), 0, stream, out_diff);
}